// Round 1
// baseline (283.100 us; speedup 1.0000x reference)
//
#include <hip/hip_runtime.h>
#include <math.h>

#define BLOCK 256
// Layer cell counts (b=32, 3 anchors):
//  L0: 32*3*13*13 = 16224  -> 64 blocks   (13x13, anchors 6,7,8)
//  L1: 32*3*26*26 = 64896  -> 254 blocks  (26x26, anchors 3,4,5)
//  L2: 32*3*52*52 = 259584 -> 1014 blocks (52x52, anchors 0,1,2)
#define NB0 64
#define NB1 254
#define NB2 1014
#define NBLOCKS (NB0 + NB1 + NB2)

// 4-byte-aligned float4: y_true rows are 340 B apart (340 % 16 == 4), so only
// dword alignment is guaranteed. gfx950 global_load_dwordx4 only needs dword
// alignment; this typedef lets the compiler emit it (load <4 x float>, align 4).
typedef float f4a __attribute__((ext_vector_type(4), aligned(4)));

// anchors ordered [layer][a]: layer0 = ANCHORS[6,7,8], layer1 = [3,4,5], layer2 = [0,1,2]
__constant__ float c_anch[9][2] = {
    {116.f, 90.f}, {156.f, 198.f}, {373.f, 326.f},
    { 30.f, 61.f}, { 62.f,  45.f}, { 59.f, 119.f},
    { 10.f, 13.f}, { 16.f,  30.f}, { 33.f,  23.f}
};

// stable softplus: log(1+exp(x)) = max(x,0) + log(1+exp(-|x|))
__device__ __forceinline__ float softplusf(float x) {
    float ax = fabsf(x);
    return fmaxf(x, 0.f) + __logf(1.f + __expf(-ax));
}

__device__ __forceinline__ float sigmoidf(float x) {
    return __fdividef(1.f, 1.f + __expf(-x));
}

__global__ __launch_bounds__(BLOCK) void yolo_loss_main(
    const float* __restrict__ p0, const float* __restrict__ p1, const float* __restrict__ p2,
    const float* __restrict__ t0, const float* __restrict__ t1, const float* __restrict__ t2,
    const float* __restrict__ tgt, float* __restrict__ partials)
{
    int blk = blockIdx.x;
    const float* pred;
    const float* tru;
    int layer, g, cells, bbase;
    if (blk < NB0)            { layer = 0; pred = p0; tru = t0; g = 13; cells = 16224;  bbase = 0; }
    else if (blk < NB0 + NB1) { layer = 1; pred = p1; tru = t1; g = 26; cells = 64896;  bbase = NB0; }
    else                      { layer = 2; pred = p2; tru = t2; g = 52; cells = 259584; bbase = NB0 + NB1; }

    int idx = (blk - bbase) * BLOCK + threadIdx.x;
    float acc = 0.f;

    if (idx < cells) {
        int hw = g * g;
        int ij = idx % hw;
        int a  = (idx / hw) % 3;
        int b  = idx / (3 * hw);
        int i  = ij / g;
        int j  = ij - i * g;

        // raw[b][a][i][j][c] = y_pred[b][a*85+c][i][j]  (channel stride = hw)
        const float* pb = pred + (size_t)((b * 3 + a) * 85) * hw + ij;
        // y_true[b][a][i][j][c]  (channel-minor, 340 B per cell, dword-aligned)
        const float* tb = tru + (size_t)((b * 3 + a) * hw + ij) * 85;

        float r0 = pb[0];
        float r1 = pb[hw];
        float r2 = pb[2 * hw];
        float r3 = pb[3 * hw];
        float r4 = pb[4 * hw];

        // vectorized head load: y0..y3 in one dwordx4, mask scalar
        f4a y03 = *reinterpret_cast<const f4a*>(tb);
        float y0 = y03.x, y1 = y03.y, y2 = y03.z, y3 = y03.w;
        float mask = tb[4];

        float gf = (float)g, gx = (float)j, gy = (float)i;
        float aw = c_anch[layer * 3 + a][0];
        float ah = c_anch[layer * 3 + a][1];

        // ---- xy loss: bce(sigmoid(r), t) = softplus(r) - t*r ----
        float true_x = y0 * gf - gx;
        float true_y = y1 * gf - gy;
        float ls = 2.f - y2 * y3;   // loss_scale
        float lxy = (softplusf(r0) - true_x * r0) + (softplusf(r1) - true_y * r1);
        acc += mask * ls * lxy;

        // ---- wh loss ----
        float tw = __logf(y2 * (416.f / aw));
        float th = __logf(y3 * (416.f / ah));
        float dw = r2 - tw, dh = r3 - th;
        acc += mask * ls * 0.5f * (dw * dw + dh * dh);

        // ---- conf bce ----
        float cbce = softplusf(r4) - mask * r4;

        // ---- IoU vs 20 targets -> neg mask (dwordx4 target loads) ----
        float sx = sigmoidf(r0);
        float sy = sigmoidf(r1);
        float bx = __fdividef(sx + gx, gf);
        float by = __fdividef(sy + gy, gf);
        float bw = __expf(r2) * aw * (1.f / 416.f);
        float bh = __expf(r3) * ah * (1.f / 416.f);
        float a1 = bw * bh;
        float b1minx = bx - 0.5f * bw, b1maxx = bx + 0.5f * bw;
        float b1miny = by - 0.5f * bh, b1maxy = by + 0.5f * bh;

        const float* tg = tgt + b * 20 * 5;
        float best = 0.f;
#pragma unroll 5
        for (int k = 0; k < 20; k++) {
            f4a t = *reinterpret_cast<const f4a*>(tg + k * 5);  // tx,ty,tw,th (5th elem unused)
            float hw2 = 0.5f * t.z, hh2 = 0.5f * t.w;
            float iw = fminf(b1maxx, t.x + hw2) - fmaxf(b1minx, t.x - hw2);
            float ih = fminf(b1maxy, t.y + hh2) - fmaxf(b1miny, t.y - hh2);
            iw = fmaxf(iw, 0.f);
            ih = fmaxf(ih, 0.f);
            float inter = iw * ih;
            float iou = __fdividef(inter, a1 + t.z * t.w - inter);
            best = fmaxf(best, iou);
        }
        float neg = (best < 0.5f) ? 1.f : 0.f;
        acc += mask * cbce + (1.f - mask) * neg * cbce;

        // ---- class loss: sum over 80 classes of mask * (softplus(x) - t*x) ----
        // y_true classes via 20 dwordx4 loads (was 80 scalar gathers: each scalar
        // load hit 64 distinct cache lines per wave — the dominant stall source).
        float cls = 0.f;
#pragma unroll 10
        for (int c4 = 0; c4 < 20; c4++) {
            f4a t = *reinterpret_cast<const f4a*>(tb + 5 + 4 * c4);
            const float* pc = pb + (size_t)(5 + 4 * c4) * hw;
            float x0 = pc[0];
            float x1 = pc[hw];
            float x2 = pc[2 * hw];
            float x3 = pc[3 * hw];
            cls += (softplusf(x0) - t.x * x0)
                 + (softplusf(x1) - t.y * x1)
                 + (softplusf(x2) - t.z * x2)
                 + (softplusf(x3) - t.w * x3);
        }
        acc += mask * cls;
    }

    // ---- block reduction: wave shuffle then LDS ----
    for (int off = 32; off > 0; off >>= 1)
        acc += __shfl_down(acc, off, 64);
    __shared__ float sh[BLOCK / 64];
    if ((threadIdx.x & 63) == 0)
        sh[threadIdx.x >> 6] = acc;
    __syncthreads();
    if (threadIdx.x == 0) {
        float s = 0.f;
        for (int wv = 0; wv < BLOCK / 64; wv++) s += sh[wv];
        partials[blockIdx.x] = s;
    }
}

__global__ __launch_bounds__(BLOCK) void yolo_loss_reduce(
    const float* __restrict__ partials, float* __restrict__ out)
{
    float s = 0.f;
    for (int i = threadIdx.x; i < NBLOCKS; i += BLOCK)
        s += partials[i];
    for (int off = 32; off > 0; off >>= 1)
        s += __shfl_down(s, off, 64);
    __shared__ float sh[BLOCK / 64];
    if ((threadIdx.x & 63) == 0)
        sh[threadIdx.x >> 6] = s;
    __syncthreads();
    if (threadIdx.x == 0) {
        float tot = 0.f;
        for (int wv = 0; wv < BLOCK / 64; wv++) tot += sh[wv];
        out[0] = tot;
    }
}

extern "C" void kernel_launch(void* const* d_in, const int* in_sizes, int n_in,
                              void* d_out, int out_size, void* d_ws, size_t ws_size,
                              hipStream_t stream) {
    // setup_inputs() dict order is INTERLEAVED:
    //   d_in[0]=y_pred0, d_in[1]=y_true0, d_in[2]=y_pred1, d_in[3]=y_true1,
    //   d_in[4]=y_pred2, d_in[5]=y_true2, d_in[6]=target
    const float* p0  = (const float*)d_in[0];
    const float* t0  = (const float*)d_in[1];
    const float* p1  = (const float*)d_in[2];
    const float* t1  = (const float*)d_in[3];
    const float* p2  = (const float*)d_in[4];
    const float* t2  = (const float*)d_in[5];
    const float* tgt = (const float*)d_in[6];
    float* partials  = (float*)d_ws;   // NBLOCKS floats; every slot written each call

    yolo_loss_main<<<NBLOCKS, BLOCK, 0, stream>>>(p0, p1, p2, t0, t1, t2, tgt, partials);
    yolo_loss_reduce<<<1, BLOCK, 0, stream>>>(partials, (float*)d_out);
}